// Round 9
// baseline (166.372 us; speedup 1.0000x reference)
//
#include <hip/hip_runtime.h>

// ---------------------------------------------------------------------------
// AttentionBlock: GroupNorm -> QKV 1x1 conv -> MHA (8 heads, d=64, N=1024)
//               -> proj 1x1 conv -> +residual
// Shapes: B=8, C=512, H=W=32 (N=1024), groups=32, heads=8, hd=64. fp32 I/O.
// R8->R9: attn PV uses v_mfma_f32_16x16x16_bf16 whose B-operand k-layout
// (k=4*(lane>>4)+j) EQUALS the S^T C-layout row (kv=4*(lane>>4)+r): P goes
// register->register into the PV MFMA, eliminating the P LDS round trip
// (-33% LDS bytes on the binding pipe). Guarded by __has_builtin; falls
// back to the R8 LDS round-trip if unavailable.
// ---------------------------------------------------------------------------

typedef __bf16 bf16;
typedef __bf16 bf16x8 __attribute__((ext_vector_type(8)));
typedef __bf16 bf16x4 __attribute__((ext_vector_type(4)));
typedef __bf16 bf16x2 __attribute__((ext_vector_type(2)));
typedef short  s16x4  __attribute__((ext_vector_type(4)));
typedef float  f32x4  __attribute__((ext_vector_type(4)));

#define MFMA_16x16x32(A, B, C) __builtin_amdgcn_mfma_f32_16x16x32_bf16((A), (B), (C), 0, 0, 0)

#if __has_builtin(__builtin_amdgcn_mfma_f32_16x16x16bf16_1k)
#define MFMA16_OK 1
static __device__ __forceinline__ f32x4 MFMA_16x16x16(bf16x4 a, bf16x4 b, f32x4 c) {
  return __builtin_amdgcn_mfma_f32_16x16x16bf16_1k(
      __builtin_bit_cast(s16x4, a), __builtin_bit_cast(s16x4, b), c, 0, 0, 0);
}
#else
#define MFMA16_OK 0
#endif

// Stage a 128-row x 32-k bf16 tile (rows stride 512 in global) into LDS via
// async global_load_lds width=16.
static __device__ __forceinline__ void async_stage_128x32(
    const bf16* __restrict__ g0, bf16* lds, int tid) {
  const int wv = tid >> 6, ln = tid & 63;
#pragma unroll
  for (int cc = 0; cc < 2; ++cc) {
    const int c = wv + cc * 4;                       // wave-uniform chunk id
    const bf16* g = g0 + (size_t)(c * 16 + (ln >> 2)) * 512 + (ln & 3) * 8;
    __builtin_amdgcn_global_load_lds(
        (const __attribute__((address_space(1))) void*)g,
        (__attribute__((address_space(3))) void*)(lds + c * 512),
        16, 0, 0);
  }
}

// 64-row variant (one 16-row chunk per wave).
static __device__ __forceinline__ void async_stage_64x32(
    const bf16* __restrict__ g0, bf16* lds, int tid) {
  const int wv = tid >> 6, ln = tid & 63;
  const bf16* g = g0 + (size_t)(wv * 16 + (ln >> 2)) * 512 + (ln & 3) * 8;
  __builtin_amdgcn_global_load_lds(
      (const __attribute__((address_space(1))) void*)g,
      (__attribute__((address_space(3))) void*)(lds + wv * 512),
      16, 0, 0);
}

// ---------------------------------------------------------------------------
// Kernel 1: fused prep: blocks [0,256) = GroupNorm stats; rest = weight cvt.
__global__ void prep_kernel(const float* __restrict__ x,
                            float* __restrict__ meanp, float* __restrict__ rstdp,
                            const float* __restrict__ qw, const float* __restrict__ pw,
                            bf16* __restrict__ wq, bf16* __restrict__ wp) {
  if (blockIdx.x >= 256) {
    const int i = (blockIdx.x - 256) * 256 + threadIdx.x;
    if (i < 1536 * 512) wq[i] = (bf16)qw[i];
    if (i < 512 * 512)  wp[i] = (bf16)pw[i];
    return;
  }
  const int bg = blockIdx.x;
  const float4* p = (const float4*)(x + (size_t)bg * 16384);
  float s = 0.f, s2 = 0.f;
#pragma unroll 4
  for (int i = threadIdx.x; i < 4096; i += 256) {
    float4 v = p[i];
    s  += (v.x + v.y) + (v.z + v.w);
    s2 += (v.x * v.x + v.y * v.y) + (v.z * v.z + v.w * v.w);
  }
#pragma unroll
  for (int d = 1; d < 64; d <<= 1) {
    s  += __shfl_xor(s,  d);
    s2 += __shfl_xor(s2, d);
  }
  __shared__ float as[4], as2[4];
  if ((threadIdx.x & 63) == 0) { as[threadIdx.x >> 6] = s; as2[threadIdx.x >> 6] = s2; }
  __syncthreads();
  if (threadIdx.x == 0) {
    float S  = as[0] + as[1] + as[2] + as[3];
    float S2 = as2[0] + as2[1] + as2[2] + as2[3];
    float m = S * (1.0f / 16384.0f);
    float v = S2 * (1.0f / 16384.0f) - m * m;
    meanp[bg] = m;
    rstdp[bg] = rsqrtf(v + 1e-5f);
  }
}

// ---------------------------------------------------------------------------
// Kernel 2: apply GN + transpose to token-major bf16 xn_t[b][n][c].
__global__ void gn_apply_kernel(const float* __restrict__ x,
                                const float* __restrict__ gn_w, const float* __restrict__ gn_b,
                                const float* __restrict__ meanp, const float* __restrict__ rstdp,
                                bf16* __restrict__ xn_t) {
  const int n0 = blockIdx.x * 64, c0 = blockIdx.y * 64, b = blockIdx.z;
  __shared__ float tile[64 * 68];
  const int t = threadIdx.x;
  const float* xb = x + ((size_t)b * 512 + c0) * 1024 + n0;
#pragma unroll
  for (int i = 0; i < 4; ++i) {
    int idx = t + i * 256;
    int cl  = idx >> 4;
    int n4  = (idx & 15) * 4;
    float4 v = *(const float4*)(xb + (size_t)cl * 1024 + n4);
    int c  = c0 + cl;
    int bg = b * 32 + (c >> 4);
    float sc = rstdp[bg] * gn_w[c];
    float sh = gn_b[c] - meanp[bg] * sc;
    tile[(n4 + 0) * 68 + cl] = v.x * sc + sh;
    tile[(n4 + 1) * 68 + cl] = v.y * sc + sh;
    tile[(n4 + 2) * 68 + cl] = v.z * sc + sh;
    tile[(n4 + 3) * 68 + cl] = v.w * sc + sh;
  }
  __syncthreads();
  bf16* ob = xn_t + ((size_t)b * 1024 + n0) * 512 + c0;
#pragma unroll
  for (int i = 0; i < 8; ++i) {                      // bf16x2 vector writes
    int idx = t + i * 256;                           // 0..2047 pair ids
    int nl = idx >> 5, cp = (idx & 31) * 2;
    bf16x2 v2 = { (bf16)tile[nl * 68 + cp], (bf16)tile[nl * 68 + cp + 1] };
    *(bf16x2*)(&ob[(size_t)nl * 512 + cp]) = v2;
  }
}

// ---------------------------------------------------------------------------
// Kernel 3: QKV GEMM, single-barrier dbuf K-loop (BK=32, 16 iters).
// Q rows (o<512) pre-scaled by 0.125*log2(e). Q,K -> qkv_t token-major;
// V -> v_t[b][h][d][n] direct transposed store.
__global__ __launch_bounds__(256) void qkv_gemm_kernel(
    const bf16* __restrict__ W, const bf16* __restrict__ xn_t,
    const float* __restrict__ qkv_b, bf16* __restrict__ qkv_t,
    bf16* __restrict__ v_t) {
  const int n0 = blockIdx.x * 128;
  const int o0 = blockIdx.y * 128;
  const int b  = blockIdx.z;
  __shared__ bf16 As[2][128 * 32];
  __shared__ bf16 Bs[2][128 * 32];
  const int tid = threadIdx.x, ln = tid & 63, wv = tid >> 6;
  const int mw = (wv >> 1) * 64, nw = (wv & 1) * 64;
  const int l15 = ln & 15, lg = ln >> 4;
  const bf16* gA = W + (size_t)o0 * 512;
  const bf16* gB = xn_t + ((size_t)b * 1024 + n0) * 512;
  f32x4 acc[4][4] = {};
  async_stage_128x32(gA, As[0], tid);
  async_stage_128x32(gB, Bs[0], tid);
  for (int it = 0; it < 16; ++it) {
    __syncthreads();                                 // publish buf[cur]
    const int cur = it & 1, nxt = cur ^ 1;
    if (it < 15) {                                   // prefetch overlaps compute
      async_stage_128x32(gA + (it + 1) * 32, As[nxt], tid);
      async_stage_128x32(gB + (it + 1) * 32, Bs[nxt], tid);
    }
    bf16x8 af[4], bfr[4];
#pragma unroll
    for (int mi = 0; mi < 4; ++mi)
      af[mi] = *(const bf16x8*)(&As[cur][(mw + mi * 16 + l15) * 32 + lg * 8]);
#pragma unroll
    for (int nj = 0; nj < 4; ++nj)
      bfr[nj] = *(const bf16x8*)(&Bs[cur][(nw + nj * 16 + l15) * 32 + lg * 8]);
#pragma unroll
    for (int mi = 0; mi < 4; ++mi)
#pragma unroll
      for (int nj = 0; nj < 4; ++nj)
        acc[mi][nj] = MFMA_16x16x32(af[mi], bfr[nj], acc[mi][nj]);
  }
  if (o0 < 1024) {
    const float qs = (o0 < 512) ? 0.125f * 1.44269504089f : 1.0f;
#pragma unroll
    for (int mi = 0; mi < 4; ++mi) {
      const int o = o0 + mw + mi * 16 + lg * 4;
      const float b0 = qkv_b[o], b1 = qkv_b[o + 1], b2 = qkv_b[o + 2], b3 = qkv_b[o + 3];
#pragma unroll
      for (int nj = 0; nj < 4; ++nj) {
        const int n = n0 + nw + nj * 16 + l15;
        f32x4 v = acc[mi][nj];
        bf16x4 st = { (bf16)((v.x + b0) * qs), (bf16)((v.y + b1) * qs),
                      (bf16)((v.z + b2) * qs), (bf16)((v.w + b3) * qs) };
        *(bf16x4*)(&qkv_t[((size_t)b * 1024 + n) * 1536 + o]) = st;
      }
    }
  } else {
#pragma unroll
    for (int mi = 0; mi < 4; ++mi) {
      const int o  = o0 + mw + mi * 16 + lg * 4;
      const int hd = o - 1024;
      const float b0 = qkv_b[o], b1 = qkv_b[o + 1], b2 = qkv_b[o + 2], b3 = qkv_b[o + 3];
      bf16* vb = v_t + ((size_t)b * 512 + hd) * 1024;
#pragma unroll
      for (int nj = 0; nj < 4; ++nj) {
        const int n = n0 + nw + nj * 16 + l15;
        f32x4 v = acc[mi][nj];
        vb[0 * 1024 + n] = (bf16)(v.x + b0);
        vb[1 * 1024 + n] = (bf16)(v.y + b1);
        vb[2 * 1024 + n] = (bf16)(v.z + b2);
        vb[3 * 1024 + n] = (bf16)(v.w + b3);
      }
    }
  }
}

// ---------------------------------------------------------------------------
// Kernel 4: fused attention: S^T/O^T, dual-kv-split, no online max, K/V
// staged in LDS with register prefetch. PV path: register-to-register P via
// 16x16x16 MFMA (B k-layout == S^T C row-layout) when available.
#if MFMA16_OK
#define ATTN_SMEM 36864
#else
#define ATTN_SMEM 73728
#endif
__global__ __launch_bounds__(512, 4) void attn_kernel(
    const bf16* __restrict__ qkv_t, const bf16* __restrict__ v_t,
    bf16* __restrict__ at_t) {
  const int qt = blockIdx.x;                        // 0..7 (128 q each)
  const int b  = blockIdx.y >> 3;
  const int h  = blockIdx.y & 7;
  __shared__ __align__(16) char smem[ATTN_SMEM];
  const int tid = threadIdx.x, ln = tid & 63, wv = tid >> 6;
  const int half = wv >> 2, w4 = wv & 3;
  const int l15 = ln & 15, g = ln >> 4;
  bf16* Kt = (bf16*)(smem + half * 18432);          // 64 x 72
  bf16* Vt = Kt + 64 * 72;                          // 64 x 72
#if !MFMA16_OK
  bf16* Pme = (bf16*)(smem + 36864) + wv * 32 * 72; // per-wave P[q][kv]
#endif
  const bf16* hq  = qkv_t + (size_t)b * 1024 * 1536 + h * 64;
  const bf16* hk  = hq + 512;
  const bf16* vtb = v_t + (size_t)(b * 8 + h) * 64 * 1024;

  const int qb = qt * 128 + w4 * 32;
  bf16x8 qf[2][2];
#pragma unroll
  for (int m = 0; m < 2; ++m)
#pragma unroll
    for (int ks = 0; ks < 2; ++ks)
      qf[m][ks] = *(const bf16x8*)(hq + (size_t)(qb + m * 16 + l15) * 1536 + ks * 32 + g * 8);

  f32x4 oacc[2][4] = {};
  float lst[2] = { 0.f, 0.f };

  const int t256 = tid & 255;
  const int srow = t256 >> 2, scg = (t256 & 3) * 16;
  const int kt0 = half * 8;
  bf16x8 kpre0 = *(const bf16x8*)(hk + (size_t)(kt0 * 64 + srow) * 1536 + scg);
  bf16x8 kpre1 = *(const bf16x8*)(hk + (size_t)(kt0 * 64 + srow) * 1536 + scg + 8);
  bf16x8 vpre0 = *(const bf16x8*)(vtb + (size_t)srow * 1024 + kt0 * 64 + scg);
  bf16x8 vpre1 = *(const bf16x8*)(vtb + (size_t)srow * 1024 + kt0 * 64 + scg + 8);

  for (int i = 0; i < 8; ++i) {
    __syncthreads();
    *(bf16x8*)(&Kt[srow * 72 + scg])     = kpre0;
    *(bf16x8*)(&Kt[srow * 72 + scg + 8]) = kpre1;
    *(bf16x8*)(&Vt[srow * 72 + scg])     = vpre0;
    *(bf16x8*)(&Vt[srow * 72 + scg + 8]) = vpre1;
    __syncthreads();
    if (i < 7) {
      const int ktn = kt0 + i + 1;
      const bf16* hk2  = hk  + (size_t)(ktn * 64 + srow) * 1536 + scg;
      const bf16* vtb2 = vtb + (size_t)srow * 1024 + ktn * 64 + scg;
      kpre0 = *(const bf16x8*)(hk2);
      kpre1 = *(const bf16x8*)(hk2 + 8);
      vpre0 = *(const bf16x8*)(vtb2);
      vpre1 = *(const bf16x8*)(vtb2 + 8);
    }

    bf16x8 kf[4][2];
#pragma unroll
    for (int kj = 0; kj < 4; ++kj)
#pragma unroll
      for (int ks = 0; ks < 2; ++ks)
        kf[kj][ks] = *(const bf16x8*)(&Kt[(kj * 16 + l15) * 72 + ks * 32 + g * 8]);

#if MFMA16_OK
    bf16x4 pe[2][4];
#endif
#pragma unroll
    for (int m = 0; m < 2; ++m) {
      f32x4 st[4] = {};
#pragma unroll
      for (int ks = 0; ks < 2; ++ks)
#pragma unroll
        for (int kj = 0; kj < 4; ++kj)
          st[kj] = MFMA_16x16x32(kf[kj][ks], qf[m][ks], st[kj]);
      float rs = 0.f;
#pragma unroll
      for (int kj = 0; kj < 4; ++kj) {
        float e0 = exp2f(st[kj][0]);
        float e1 = exp2f(st[kj][1]);
        float e2 = exp2f(st[kj][2]);
        float e3 = exp2f(st[kj][3]);
        rs += (e0 + e1) + (e2 + e3);
        bf16x4 p4 = { (bf16)e0, (bf16)e1, (bf16)e2, (bf16)e3 };
#if MFMA16_OK
        pe[m][kj] = p4;                              // stays in registers
#else
        *(bf16x4*)(&Pme[(m * 16 + l15) * 72 + kj * 16 + g * 4]) = p4;
#endif
      }
      lst[m] += rs;
    }

#if MFMA16_OK
    // O'^T += V^T P^T via 16x16x16: pe IS the B-fragment (k=4g+j == C-row).
#pragma unroll
    for (int kj = 0; kj < 4; ++kj)
#pragma unroll
      for (int dt = 0; dt < 4; ++dt) {
        bf16x4 vf4 = *(const bf16x4*)(&Vt[(dt * 16 + l15) * 72 + kj * 16 + g * 4]);
#pragma unroll
        for (int m = 0; m < 2; ++m)
          oacc[m][dt] = MFMA_16x16x16(vf4, pe[m][kj], oacc[m][dt]);
      }
#else
#pragma unroll
    for (int ks = 0; ks < 2; ++ks) {
      bf16x8 vf[4];
#pragma unroll
      for (int dt = 0; dt < 4; ++dt)
        vf[dt] = *(const bf16x8*)(&Vt[(dt * 16 + l15) * 72 + ks * 32 + g * 8]);
#pragma unroll
      for (int m = 0; m < 2; ++m) {
        bf16x8 pf = *(const bf16x8*)(&Pme[(m * 16 + l15) * 72 + ks * 32 + g * 8]);
#pragma unroll
        for (int dt = 0; dt < 4; ++dt)
          oacc[m][dt] = MFMA_16x16x32(vf[dt], pf, oacc[m][dt]);
      }
    }
#endif
  }

  float lfull[2];
#pragma unroll
  for (int m = 0; m < 2; ++m) {
    float l = lst[m];
    l += __shfl_xor(l, 16);
    l += __shfl_xor(l, 32);
    lfull[m] = l;
  }

  // merge halves (plain sums) via LDS, reusing staging region
  float* MB  = (float*)smem;                        // [w4][32 q][68 d-stride]
#if MFMA16_OK
  float* MLb = (float*)(smem + 34816);              // [w4][32]
#else
  float* MLb = (float*)(smem + 36864);              // [w4][32]
#endif
  __syncthreads();
  if (half == 1) {
    float* mb = MB + w4 * (32 * 68);
#pragma unroll
    for (int m = 0; m < 2; ++m) {
#pragma unroll
      for (int dt = 0; dt < 4; ++dt)
        *(f32x4*)(mb + (m * 16 + l15) * 68 + dt * 16 + g * 4) = oacc[m][dt];
      if (g == 0) MLb[w4 * 32 + (m * 16 + l15)] = lfull[m];
    }
  }
  __syncthreads();
  if (half == 0) {
    const float* mb = MB + w4 * (32 * 68);
#pragma unroll
    for (int m = 0; m < 2; ++m) {
      const float lB  = MLb[w4 * 32 + (m * 16 + l15)];
      const float inv = 1.0f / (lfull[m] + lB);
      const int q = qb + m * 16 + l15;
#pragma unroll
      for (int dt = 0; dt < 4; ++dt) {
        f32x4 ob = *(const f32x4*)(mb + (m * 16 + l15) * 68 + dt * 16 + g * 4);
        bf16x4 ov = { (bf16)((oacc[m][dt][0] + ob[0]) * inv),
                      (bf16)((oacc[m][dt][1] + ob[1]) * inv),
                      (bf16)((oacc[m][dt][2] + ob[2]) * inv),
                      (bf16)((oacc[m][dt][3] + ob[3]) * inv) };
        *(bf16x4*)(&at_t[((size_t)b * 1024 + q) * 512 + h * 64 + dt * 16 + g * 4]) = ov;
      }
    }
  }
}

// ---------------------------------------------------------------------------
// Kernel 5: proj GEMM + bias + residual. BM=64, single-barrier dbuf (BK=32).
__global__ __launch_bounds__(256) void proj_gemm_kernel(
    const bf16* __restrict__ at_t, const bf16* __restrict__ wp,
    const float* __restrict__ proj_b, const float* __restrict__ x,
    float* __restrict__ out) {
  const int i0 = blockIdx.x * 64;                   // token tile (64)
  const int c0 = blockIdx.y * 128;                  // out-channel tile (128)
  const int b  = blockIdx.z;
  __shared__ bf16 As[2][64 * 32];
  __shared__ bf16 Bs[2][128 * 32];
  const int tid = threadIdx.x, ln = tid & 63, wv = tid >> 6;
  const int mw = (wv >> 1) * 32, nw = (wv & 1) * 64;
  const int l15 = ln & 15, lg = ln >> 4;
  const bf16* gA = at_t + ((size_t)b * 1024 + i0) * 512;
  const bf16* gB = wp + (size_t)c0 * 512;
  f32x4 acc[2][4] = {};
  async_stage_64x32(gA, As[0], tid);
  async_stage_128x32(gB, Bs[0], tid);
  for (int it = 0; it < 16; ++it) {
    __syncthreads();
    const int cur = it & 1, nxt = cur ^ 1;
    if (it < 15) {
      async_stage_64x32(gA + (it + 1) * 32, As[nxt], tid);
      async_stage_128x32(gB + (it + 1) * 32, Bs[nxt], tid);
    }
    bf16x8 af[2], bfr[4];
#pragma unroll
    for (int mi = 0; mi < 2; ++mi)
      af[mi] = *(const bf16x8*)(&As[cur][(mw + mi * 16 + l15) * 32 + lg * 8]);
#pragma unroll
    for (int nj = 0; nj < 4; ++nj)
      bfr[nj] = *(const bf16x8*)(&Bs[cur][(nw + nj * 16 + l15) * 32 + lg * 8]);
#pragma unroll
    for (int mi = 0; mi < 2; ++mi)
#pragma unroll
      for (int nj = 0; nj < 4; ++nj)
        acc[mi][nj] = MFMA_16x16x32(af[mi], bfr[nj], acc[mi][nj]);
  }
#pragma unroll
  for (int mi = 0; mi < 2; ++mi) {
    const int i = i0 + mw + mi * 16 + lg * 4;
#pragma unroll
    for (int nj = 0; nj < 4; ++nj) {
      const int c = c0 + nw + nj * 16 + l15;
      const float bias = proj_b[c];
      const size_t off = ((size_t)b * 512 + c) * 1024 + i;
      const float4 res = *(const float4*)(x + off);
      f32x4 v = acc[mi][nj];
      float4 ov;
      ov.x = v.x + bias + res.x;
      ov.y = v.y + bias + res.y;
      ov.z = v.z + bias + res.z;
      ov.w = v.w + bias + res.w;
      *(float4*)(out + off) = ov;
    }
  }
}

// ---------------------------------------------------------------------------
extern "C" void kernel_launch(void* const* d_in, const int* in_sizes, int n_in,
                              void* d_out, int out_size, void* d_ws, size_t ws_size,
                              hipStream_t stream) {
  (void)in_sizes; (void)n_in; (void)out_size; (void)ws_size;
  const float* x      = (const float*)d_in[0];
  const float* gn_w   = (const float*)d_in[1];
  const float* gn_b   = (const float*)d_in[2];
  const float* qkv_w  = (const float*)d_in[3];
  const float* qkv_b  = (const float*)d_in[4];
  const float* proj_w = (const float*)d_in[5];
  const float* proj_b = (const float*)d_in[6];
  float* out = (float*)d_out;

  // workspace layout (~50 MB)
  char* ws = (char*)d_ws;
  float* meanp = (float*)ws;                        // 256 f32
  float* rstdp = meanp + 256;                       // 256 f32
  bf16* wq    = (bf16*)(ws + 4096);                 // [1536][512]
  bf16* wp    = wq + (size_t)1536 * 512;            // [512][512]
  bf16* xn_t  = wp + (size_t)512 * 512;             // [8][1024][512]
  bf16* qkv_t = xn_t + (size_t)8 * 1024 * 512;      // [8][1024][1536] (Q,K only)
  bf16* at_t  = qkv_t + (size_t)8 * 1024 * 1536;    // [8][1024][512]
  bf16* v_t   = at_t + (size_t)8 * 1024 * 512;      // [8][8][64][1024]

  hipLaunchKernelGGL(prep_kernel,     dim3(3328),      dim3(256), 0, stream,
                     x, meanp, rstdp, qkv_w, proj_w, wq, wp);
  hipLaunchKernelGGL(gn_apply_kernel, dim3(16, 8, 8),  dim3(256), 0, stream,
                     x, gn_w, gn_b, meanp, rstdp, xn_t);
  hipLaunchKernelGGL(qkv_gemm_kernel, dim3(8, 12, 8),  dim3(256), 0, stream,
                     wq, xn_t, qkv_b, qkv_t, v_t);
  hipLaunchKernelGGL(attn_kernel,     dim3(8, 64),     dim3(512), 0, stream,
                     qkv_t, v_t, at_t);
  hipLaunchKernelGGL(proj_gemm_kernel,dim3(16, 4, 8),  dim3(256), 0, stream,
                     at_t, wp, proj_b, x, out);
}

// Round 10
// 160.762 us; speedup vs baseline: 1.0349x; 1.0349x over previous
//
#include <hip/hip_runtime.h>

// ---------------------------------------------------------------------------
// AttentionBlock: GroupNorm -> QKV 1x1 conv -> MHA (8 heads, d=64, N=1024)
//               -> proj 1x1 conv -> +residual
// Shapes: B=8, C=512, H=W=32 (N=1024), groups=32, heads=8, hd=64. fp32 I/O.
// R9->R10: revert K16 register-P experiment (doubled PV MFMA issue, lost).
// attn grid swapped to (bh, qt) so XCD = bh%8: all 8 q-tile blocks of a head
// share one XCD's L2 (K/V working set 2MB < 4MB L2) instead of thrashing
// (old layout: XCD = qt%8 -> 16MB/XCD -> 80MB HBM fetch).
// ---------------------------------------------------------------------------

typedef __bf16 bf16;
typedef __bf16 bf16x8 __attribute__((ext_vector_type(8)));
typedef __bf16 bf16x4 __attribute__((ext_vector_type(4)));
typedef __bf16 bf16x2 __attribute__((ext_vector_type(2)));
typedef float  f32x4  __attribute__((ext_vector_type(4)));

#define MFMA_16x16x32(A, B, C) __builtin_amdgcn_mfma_f32_16x16x32_bf16((A), (B), (C), 0, 0, 0)

// Stage a 128-row x 32-k bf16 tile (rows stride 512 in global) into LDS via
// async global_load_lds width=16.
static __device__ __forceinline__ void async_stage_128x32(
    const bf16* __restrict__ g0, bf16* lds, int tid) {
  const int wv = tid >> 6, ln = tid & 63;
#pragma unroll
  for (int cc = 0; cc < 2; ++cc) {
    const int c = wv + cc * 4;                       // wave-uniform chunk id
    const bf16* g = g0 + (size_t)(c * 16 + (ln >> 2)) * 512 + (ln & 3) * 8;
    __builtin_amdgcn_global_load_lds(
        (const __attribute__((address_space(1))) void*)g,
        (__attribute__((address_space(3))) void*)(lds + c * 512),
        16, 0, 0);
  }
}

// 64-row variant (one 16-row chunk per wave).
static __device__ __forceinline__ void async_stage_64x32(
    const bf16* __restrict__ g0, bf16* lds, int tid) {
  const int wv = tid >> 6, ln = tid & 63;
  const bf16* g = g0 + (size_t)(wv * 16 + (ln >> 2)) * 512 + (ln & 3) * 8;
  __builtin_amdgcn_global_load_lds(
      (const __attribute__((address_space(1))) void*)g,
      (__attribute__((address_space(3))) void*)(lds + wv * 512),
      16, 0, 0);
}

// ---------------------------------------------------------------------------
// Kernel 1: fused prep: blocks [0,256) = GroupNorm stats; rest = weight cvt.
__global__ void prep_kernel(const float* __restrict__ x,
                            float* __restrict__ meanp, float* __restrict__ rstdp,
                            const float* __restrict__ qw, const float* __restrict__ pw,
                            bf16* __restrict__ wq, bf16* __restrict__ wp) {
  if (blockIdx.x >= 256) {
    const int i = (blockIdx.x - 256) * 256 + threadIdx.x;
    if (i < 1536 * 512) wq[i] = (bf16)qw[i];
    if (i < 512 * 512)  wp[i] = (bf16)pw[i];
    return;
  }
  const int bg = blockIdx.x;
  const float4* p = (const float4*)(x + (size_t)bg * 16384);
  float s = 0.f, s2 = 0.f;
#pragma unroll 4
  for (int i = threadIdx.x; i < 4096; i += 256) {
    float4 v = p[i];
    s  += (v.x + v.y) + (v.z + v.w);
    s2 += (v.x * v.x + v.y * v.y) + (v.z * v.z + v.w * v.w);
  }
#pragma unroll
  for (int d = 1; d < 64; d <<= 1) {
    s  += __shfl_xor(s,  d);
    s2 += __shfl_xor(s2, d);
  }
  __shared__ float as[4], as2[4];
  if ((threadIdx.x & 63) == 0) { as[threadIdx.x >> 6] = s; as2[threadIdx.x >> 6] = s2; }
  __syncthreads();
  if (threadIdx.x == 0) {
    float S  = as[0] + as[1] + as[2] + as[3];
    float S2 = as2[0] + as2[1] + as2[2] + as2[3];
    float m = S * (1.0f / 16384.0f);
    float v = S2 * (1.0f / 16384.0f) - m * m;
    meanp[bg] = m;
    rstdp[bg] = rsqrtf(v + 1e-5f);
  }
}

// ---------------------------------------------------------------------------
// Kernel 2: apply GN + transpose to token-major bf16 xn_t[b][n][c].
__global__ void gn_apply_kernel(const float* __restrict__ x,
                                const float* __restrict__ gn_w, const float* __restrict__ gn_b,
                                const float* __restrict__ meanp, const float* __restrict__ rstdp,
                                bf16* __restrict__ xn_t) {
  const int n0 = blockIdx.x * 64, c0 = blockIdx.y * 64, b = blockIdx.z;
  __shared__ float tile[64 * 68];
  const int t = threadIdx.x;
  const float* xb = x + ((size_t)b * 512 + c0) * 1024 + n0;
#pragma unroll
  for (int i = 0; i < 4; ++i) {
    int idx = t + i * 256;
    int cl  = idx >> 4;
    int n4  = (idx & 15) * 4;
    float4 v = *(const float4*)(xb + (size_t)cl * 1024 + n4);
    int c  = c0 + cl;
    int bg = b * 32 + (c >> 4);
    float sc = rstdp[bg] * gn_w[c];
    float sh = gn_b[c] - meanp[bg] * sc;
    tile[(n4 + 0) * 68 + cl] = v.x * sc + sh;
    tile[(n4 + 1) * 68 + cl] = v.y * sc + sh;
    tile[(n4 + 2) * 68 + cl] = v.z * sc + sh;
    tile[(n4 + 3) * 68 + cl] = v.w * sc + sh;
  }
  __syncthreads();
  bf16* ob = xn_t + ((size_t)b * 1024 + n0) * 512 + c0;
#pragma unroll
  for (int i = 0; i < 8; ++i) {                      // bf16x2 vector writes
    int idx = t + i * 256;                           // 0..2047 pair ids
    int nl = idx >> 5, cp = (idx & 31) * 2;
    bf16x2 v2 = { (bf16)tile[nl * 68 + cp], (bf16)tile[nl * 68 + cp + 1] };
    *(bf16x2*)(&ob[(size_t)nl * 512 + cp]) = v2;
  }
}

// ---------------------------------------------------------------------------
// Kernel 3: QKV GEMM, single-barrier dbuf K-loop (BK=32, 16 iters).
// Q rows (o<512) pre-scaled by 0.125*log2(e). Q,K -> qkv_t token-major;
// V -> v_t[b][h][d][n] direct transposed store.
__global__ __launch_bounds__(256) void qkv_gemm_kernel(
    const bf16* __restrict__ W, const bf16* __restrict__ xn_t,
    const float* __restrict__ qkv_b, bf16* __restrict__ qkv_t,
    bf16* __restrict__ v_t) {
  const int n0 = blockIdx.x * 128;
  const int o0 = blockIdx.y * 128;
  const int b  = blockIdx.z;
  __shared__ bf16 As[2][128 * 32];
  __shared__ bf16 Bs[2][128 * 32];
  const int tid = threadIdx.x, ln = tid & 63, wv = tid >> 6;
  const int mw = (wv >> 1) * 64, nw = (wv & 1) * 64;
  const int l15 = ln & 15, lg = ln >> 4;
  const bf16* gA = W + (size_t)o0 * 512;
  const bf16* gB = xn_t + ((size_t)b * 1024 + n0) * 512;
  f32x4 acc[4][4] = {};
  async_stage_128x32(gA, As[0], tid);
  async_stage_128x32(gB, Bs[0], tid);
  for (int it = 0; it < 16; ++it) {
    __syncthreads();                                 // publish buf[cur]
    const int cur = it & 1, nxt = cur ^ 1;
    if (it < 15) {                                   // prefetch overlaps compute
      async_stage_128x32(gA + (it + 1) * 32, As[nxt], tid);
      async_stage_128x32(gB + (it + 1) * 32, Bs[nxt], tid);
    }
    bf16x8 af[4], bfr[4];
#pragma unroll
    for (int mi = 0; mi < 4; ++mi)
      af[mi] = *(const bf16x8*)(&As[cur][(mw + mi * 16 + l15) * 32 + lg * 8]);
#pragma unroll
    for (int nj = 0; nj < 4; ++nj)
      bfr[nj] = *(const bf16x8*)(&Bs[cur][(nw + nj * 16 + l15) * 32 + lg * 8]);
#pragma unroll
    for (int mi = 0; mi < 4; ++mi)
#pragma unroll
      for (int nj = 0; nj < 4; ++nj)
        acc[mi][nj] = MFMA_16x16x32(af[mi], bfr[nj], acc[mi][nj]);
  }
  if (o0 < 1024) {
    const float qs = (o0 < 512) ? 0.125f * 1.44269504089f : 1.0f;
#pragma unroll
    for (int mi = 0; mi < 4; ++mi) {
      const int o = o0 + mw + mi * 16 + lg * 4;
      const float b0 = qkv_b[o], b1 = qkv_b[o + 1], b2 = qkv_b[o + 2], b3 = qkv_b[o + 3];
#pragma unroll
      for (int nj = 0; nj < 4; ++nj) {
        const int n = n0 + nw + nj * 16 + l15;
        f32x4 v = acc[mi][nj];
        bf16x4 st = { (bf16)((v.x + b0) * qs), (bf16)((v.y + b1) * qs),
                      (bf16)((v.z + b2) * qs), (bf16)((v.w + b3) * qs) };
        *(bf16x4*)(&qkv_t[((size_t)b * 1024 + n) * 1536 + o]) = st;
      }
    }
  } else {
#pragma unroll
    for (int mi = 0; mi < 4; ++mi) {
      const int o  = o0 + mw + mi * 16 + lg * 4;
      const int hd = o - 1024;
      const float b0 = qkv_b[o], b1 = qkv_b[o + 1], b2 = qkv_b[o + 2], b3 = qkv_b[o + 3];
      bf16* vb = v_t + ((size_t)b * 512 + hd) * 1024;
#pragma unroll
      for (int nj = 0; nj < 4; ++nj) {
        const int n = n0 + nw + nj * 16 + l15;
        f32x4 v = acc[mi][nj];
        vb[0 * 1024 + n] = (bf16)(v.x + b0);
        vb[1 * 1024 + n] = (bf16)(v.y + b1);
        vb[2 * 1024 + n] = (bf16)(v.z + b2);
        vb[3 * 1024 + n] = (bf16)(v.w + b3);
      }
    }
  }
}

// ---------------------------------------------------------------------------
// Kernel 4: fused attention (R8 structure): S^T/O^T, dual-kv-split, no online
// max, K/V staged in LDS with register prefetch. Grid (bh, qt) so that
// XCD = bh%8: a head's 8 q-tile blocks share one XCD's L2.
__global__ __launch_bounds__(512, 4) void attn_kernel(
    const bf16* __restrict__ qkv_t, const bf16* __restrict__ v_t,
    bf16* __restrict__ at_t) {
  const int qt = blockIdx.y;                        // 0..7 (128 q each)
  const int b  = blockIdx.x >> 3;
  const int h  = blockIdx.x & 7;
  __shared__ __align__(16) char smem[73728];
  const int tid = threadIdx.x, ln = tid & 63, wv = tid >> 6;
  const int half = wv >> 2, w4 = wv & 3;
  const int l15 = ln & 15, g = ln >> 4;
  bf16* Kt = (bf16*)(smem + half * 18432);          // 64 x 72
  bf16* Vt = Kt + 64 * 72;                          // 64 x 72
  bf16* Pme = (bf16*)(smem + 36864) + wv * 32 * 72; // per-wave P[q][kv]
  const bf16* hq  = qkv_t + (size_t)b * 1024 * 1536 + h * 64;
  const bf16* hk  = hq + 512;
  const bf16* vtb = v_t + (size_t)(b * 8 + h) * 64 * 1024;

  const int qb = qt * 128 + w4 * 32;
  bf16x8 qf[2][2];
#pragma unroll
  for (int m = 0; m < 2; ++m)
#pragma unroll
    for (int ks = 0; ks < 2; ++ks)
      qf[m][ks] = *(const bf16x8*)(hq + (size_t)(qb + m * 16 + l15) * 1536 + ks * 32 + g * 8);

  f32x4 oacc[2][4] = {};
  float lst[2] = { 0.f, 0.f };

  const int t256 = tid & 255;
  const int srow = t256 >> 2, scg = (t256 & 3) * 16;
  const int kt0 = half * 8;
  bf16x8 kpre0 = *(const bf16x8*)(hk + (size_t)(kt0 * 64 + srow) * 1536 + scg);
  bf16x8 kpre1 = *(const bf16x8*)(hk + (size_t)(kt0 * 64 + srow) * 1536 + scg + 8);
  bf16x8 vpre0 = *(const bf16x8*)(vtb + (size_t)srow * 1024 + kt0 * 64 + scg);
  bf16x8 vpre1 = *(const bf16x8*)(vtb + (size_t)srow * 1024 + kt0 * 64 + scg + 8);

  for (int i = 0; i < 8; ++i) {
    __syncthreads();
    *(bf16x8*)(&Kt[srow * 72 + scg])     = kpre0;
    *(bf16x8*)(&Kt[srow * 72 + scg + 8]) = kpre1;
    *(bf16x8*)(&Vt[srow * 72 + scg])     = vpre0;
    *(bf16x8*)(&Vt[srow * 72 + scg + 8]) = vpre1;
    __syncthreads();
    if (i < 7) {
      const int ktn = kt0 + i + 1;
      const bf16* hk2  = hk  + (size_t)(ktn * 64 + srow) * 1536 + scg;
      const bf16* vtb2 = vtb + (size_t)srow * 1024 + ktn * 64 + scg;
      kpre0 = *(const bf16x8*)(hk2);
      kpre1 = *(const bf16x8*)(hk2 + 8);
      vpre0 = *(const bf16x8*)(vtb2);
      vpre1 = *(const bf16x8*)(vtb2 + 8);
    }

    bf16x8 kf[4][2];
#pragma unroll
    for (int kj = 0; kj < 4; ++kj)
#pragma unroll
      for (int ks = 0; ks < 2; ++ks)
        kf[kj][ks] = *(const bf16x8*)(&Kt[(kj * 16 + l15) * 72 + ks * 32 + g * 8]);

#pragma unroll
    for (int m = 0; m < 2; ++m) {
      f32x4 st[4] = {};
#pragma unroll
      for (int ks = 0; ks < 2; ++ks)
#pragma unroll
        for (int kj = 0; kj < 4; ++kj)
          st[kj] = MFMA_16x16x32(kf[kj][ks], qf[m][ks], st[kj]);
      float rs = 0.f;
#pragma unroll
      for (int kj = 0; kj < 4; ++kj) {
        float e0 = exp2f(st[kj][0]);
        float e1 = exp2f(st[kj][1]);
        float e2 = exp2f(st[kj][2]);
        float e3 = exp2f(st[kj][3]);
        rs += (e0 + e1) + (e2 + e3);
        bf16x4 pe = { (bf16)e0, (bf16)e1, (bf16)e2, (bf16)e3 };
        *(bf16x4*)(&Pme[(m * 16 + l15) * 72 + kj * 16 + g * 4]) = pe;
      }
      lst[m] += rs;
    }

#pragma unroll
    for (int ks = 0; ks < 2; ++ks) {
      bf16x8 vf[4];
#pragma unroll
      for (int dt = 0; dt < 4; ++dt)
        vf[dt] = *(const bf16x8*)(&Vt[(dt * 16 + l15) * 72 + ks * 32 + g * 8]);
#pragma unroll
      for (int m = 0; m < 2; ++m) {
        bf16x8 pf = *(const bf16x8*)(&Pme[(m * 16 + l15) * 72 + ks * 32 + g * 8]);
#pragma unroll
        for (int dt = 0; dt < 4; ++dt)
          oacc[m][dt] = MFMA_16x16x32(vf[dt], pf, oacc[m][dt]);
      }
    }
  }

  float lfull[2];
#pragma unroll
  for (int m = 0; m < 2; ++m) {
    float l = lst[m];
    l += __shfl_xor(l, 16);
    l += __shfl_xor(l, 32);
    lfull[m] = l;
  }

  float* MB  = (float*)smem;                        // [w4][32 q][68 d-stride]
  float* MLb = (float*)(smem + 36864);              // [w4][32]
  __syncthreads();
  if (half == 1) {
    float* mb = MB + w4 * (32 * 68);
#pragma unroll
    for (int m = 0; m < 2; ++m) {
#pragma unroll
      for (int dt = 0; dt < 4; ++dt)
        *(f32x4*)(mb + (m * 16 + l15) * 68 + dt * 16 + g * 4) = oacc[m][dt];
      if (g == 0) MLb[w4 * 32 + (m * 16 + l15)] = lfull[m];
    }
  }
  __syncthreads();
  if (half == 0) {
    const float* mb = MB + w4 * (32 * 68);
#pragma unroll
    for (int m = 0; m < 2; ++m) {
      const float lB  = MLb[w4 * 32 + (m * 16 + l15)];
      const float inv = 1.0f / (lfull[m] + lB);
      const int q = qb + m * 16 + l15;
#pragma unroll
      for (int dt = 0; dt < 4; ++dt) {
        f32x4 ob = *(const f32x4*)(mb + (m * 16 + l15) * 68 + dt * 16 + g * 4);
        bf16x4 ov = { (bf16)((oacc[m][dt][0] + ob[0]) * inv),
                      (bf16)((oacc[m][dt][1] + ob[1]) * inv),
                      (bf16)((oacc[m][dt][2] + ob[2]) * inv),
                      (bf16)((oacc[m][dt][3] + ob[3]) * inv) };
        *(bf16x4*)(&at_t[((size_t)b * 1024 + q) * 512 + h * 64 + dt * 16 + g * 4]) = ov;
      }
    }
  }
}

// ---------------------------------------------------------------------------
// Kernel 5: proj GEMM + bias + residual. BM=64, single-barrier dbuf (BK=32).
__global__ __launch_bounds__(256) void proj_gemm_kernel(
    const bf16* __restrict__ at_t, const bf16* __restrict__ wp,
    const float* __restrict__ proj_b, const float* __restrict__ x,
    float* __restrict__ out) {
  const int i0 = blockIdx.x * 64;                   // token tile (64)
  const int c0 = blockIdx.y * 128;                  // out-channel tile (128)
  const int b  = blockIdx.z;
  __shared__ bf16 As[2][64 * 32];
  __shared__ bf16 Bs[2][128 * 32];
  const int tid = threadIdx.x, ln = tid & 63, wv = tid >> 6;
  const int mw = (wv >> 1) * 32, nw = (wv & 1) * 64;
  const int l15 = ln & 15, lg = ln >> 4;
  const bf16* gA = at_t + ((size_t)b * 1024 + i0) * 512;
  const bf16* gB = wp + (size_t)c0 * 512;
  f32x4 acc[2][4] = {};
  async_stage_64x32(gA, As[0], tid);
  async_stage_128x32(gB, Bs[0], tid);
  for (int it = 0; it < 16; ++it) {
    __syncthreads();
    const int cur = it & 1, nxt = cur ^ 1;
    if (it < 15) {
      async_stage_64x32(gA + (it + 1) * 32, As[nxt], tid);
      async_stage_128x32(gB + (it + 1) * 32, Bs[nxt], tid);
    }
    bf16x8 af[2], bfr[4];
#pragma unroll
    for (int mi = 0; mi < 2; ++mi)
      af[mi] = *(const bf16x8*)(&As[cur][(mw + mi * 16 + l15) * 32 + lg * 8]);
#pragma unroll
    for (int nj = 0; nj < 4; ++nj)
      bfr[nj] = *(const bf16x8*)(&Bs[cur][(nw + nj * 16 + l15) * 32 + lg * 8]);
#pragma unroll
    for (int mi = 0; mi < 2; ++mi)
#pragma unroll
      for (int nj = 0; nj < 4; ++nj)
        acc[mi][nj] = MFMA_16x16x32(af[mi], bfr[nj], acc[mi][nj]);
  }
#pragma unroll
  for (int mi = 0; mi < 2; ++mi) {
    const int i = i0 + mw + mi * 16 + lg * 4;
#pragma unroll
    for (int nj = 0; nj < 4; ++nj) {
      const int c = c0 + nw + nj * 16 + l15;
      const float bias = proj_b[c];
      const size_t off = ((size_t)b * 512 + c) * 1024 + i;
      const float4 res = *(const float4*)(x + off);
      f32x4 v = acc[mi][nj];
      float4 ov;
      ov.x = v.x + bias + res.x;
      ov.y = v.y + bias + res.y;
      ov.z = v.z + bias + res.z;
      ov.w = v.w + bias + res.w;
      *(float4*)(out + off) = ov;
    }
  }
}

// ---------------------------------------------------------------------------
extern "C" void kernel_launch(void* const* d_in, const int* in_sizes, int n_in,
                              void* d_out, int out_size, void* d_ws, size_t ws_size,
                              hipStream_t stream) {
  (void)in_sizes; (void)n_in; (void)out_size; (void)ws_size;
  const float* x      = (const float*)d_in[0];
  const float* gn_w   = (const float*)d_in[1];
  const float* gn_b   = (const float*)d_in[2];
  const float* qkv_w  = (const float*)d_in[3];
  const float* qkv_b  = (const float*)d_in[4];
  const float* proj_w = (const float*)d_in[5];
  const float* proj_b = (const float*)d_in[6];
  float* out = (float*)d_out;

  // workspace layout (~50 MB)
  char* ws = (char*)d_ws;
  float* meanp = (float*)ws;                        // 256 f32
  float* rstdp = meanp + 256;                       // 256 f32
  bf16* wq    = (bf16*)(ws + 4096);                 // [1536][512]
  bf16* wp    = wq + (size_t)1536 * 512;            // [512][512]
  bf16* xn_t  = wp + (size_t)512 * 512;             // [8][1024][512]
  bf16* qkv_t = xn_t + (size_t)8 * 1024 * 512;      // [8][1024][1536] (Q,K only)
  bf16* at_t  = qkv_t + (size_t)8 * 1024 * 1536;    // [8][1024][512]
  bf16* v_t   = at_t + (size_t)8 * 1024 * 512;      // [8][8][64][1024]

  hipLaunchKernelGGL(prep_kernel,     dim3(3328),      dim3(256), 0, stream,
                     x, meanp, rstdp, qkv_w, proj_w, wq, wp);
  hipLaunchKernelGGL(gn_apply_kernel, dim3(16, 8, 8),  dim3(256), 0, stream,
                     x, gn_w, gn_b, meanp, rstdp, xn_t);
  hipLaunchKernelGGL(qkv_gemm_kernel, dim3(8, 12, 8),  dim3(256), 0, stream,
                     wq, xn_t, qkv_b, qkv_t, v_t);
  hipLaunchKernelGGL(attn_kernel,     dim3(64, 8),     dim3(512), 0, stream,
                     qkv_t, v_t, at_t);
  hipLaunchKernelGGL(proj_gemm_kernel,dim3(16, 4, 8),  dim3(256), 0, stream,
                     at_t, wp, proj_b, x, out);
}

// Round 11
// 157.250 us; speedup vs baseline: 1.0580x; 1.0223x over previous
//
#include <hip/hip_runtime.h>

// ---------------------------------------------------------------------------
// AttentionBlock: GroupNorm -> QKV 1x1 conv -> MHA (8 heads, d=64, N=1024)
//               -> proj 1x1 conv -> +residual
// Shapes: B=8, C=512, H=W=32 (N=1024), groups=32, heads=8, hd=64. fp32 I/O.
// R10->R11: GroupNorm stats+apply FUSED into one kernel (x read from HBM
// once, slice held in registers: 64 f32/thread); gn_apply kernel and
// mean/rstd globals removed -> 4 launches. qkv V-blocks swap MFMA operand
// order so V epilogue is 16 bf16x4 vector stores instead of 64 scalar.
// ---------------------------------------------------------------------------

typedef __bf16 bf16;
typedef __bf16 bf16x8 __attribute__((ext_vector_type(8)));
typedef __bf16 bf16x4 __attribute__((ext_vector_type(4)));
typedef float  f32x4  __attribute__((ext_vector_type(4)));

#define MFMA_16x16x32(A, B, C) __builtin_amdgcn_mfma_f32_16x16x32_bf16((A), (B), (C), 0, 0, 0)

// Stage a 128-row x 32-k bf16 tile (rows stride 512 in global) into LDS via
// async global_load_lds width=16.
static __device__ __forceinline__ void async_stage_128x32(
    const bf16* __restrict__ g0, bf16* lds, int tid) {
  const int wv = tid >> 6, ln = tid & 63;
#pragma unroll
  for (int cc = 0; cc < 2; ++cc) {
    const int c = wv + cc * 4;                       // wave-uniform chunk id
    const bf16* g = g0 + (size_t)(c * 16 + (ln >> 2)) * 512 + (ln & 3) * 8;
    __builtin_amdgcn_global_load_lds(
        (const __attribute__((address_space(1))) void*)g,
        (__attribute__((address_space(3))) void*)(lds + c * 512),
        16, 0, 0);
  }
}

// 64-row variant (one 16-row chunk per wave).
static __device__ __forceinline__ void async_stage_64x32(
    const bf16* __restrict__ g0, bf16* lds, int tid) {
  const int wv = tid >> 6, ln = tid & 63;
  const bf16* g = g0 + (size_t)(wv * 16 + (ln >> 2)) * 512 + (ln & 3) * 8;
  __builtin_amdgcn_global_load_lds(
      (const __attribute__((address_space(1))) void*)g,
      (__attribute__((address_space(3))) void*)(lds + wv * 512),
      16, 0, 0);
}

// ---------------------------------------------------------------------------
// Kernel 1: fused GroupNorm (stats + apply + transpose) and weight cvt.
// Blocks [0,256): block bg=(b,g) owns 16 channels x 1024 tokens held in
// registers (thread t: c=0..15 at n=4t..4t+3); one HBM read of x total.
// Blocks [256, 256+1024): fp32->bf16 weight conversion (float4).
__global__ __launch_bounds__(256) void gn_fused_kernel(
    const float* __restrict__ x,
    const float* __restrict__ gn_w, const float* __restrict__ gn_b,
    const float* __restrict__ qw, const float* __restrict__ pw,
    bf16* __restrict__ wq, bf16* __restrict__ wp, bf16* __restrict__ xn_t) {
  const int t = threadIdx.x;
  if (blockIdx.x >= 256) {
    const int idx = (blockIdx.x - 256) * 256 + t;    // float4 id
    if (idx < 196608) {                              // 1536*512/4
      float4 v = ((const float4*)qw)[idx];
      bf16x4 o = { (bf16)v.x, (bf16)v.y, (bf16)v.z, (bf16)v.w };
      *(bf16x4*)(&wq[idx * 4]) = o;
    }
    if (idx < 65536) {                               // 512*512/4
      float4 v = ((const float4*)pw)[idx];
      bf16x4 o = { (bf16)v.x, (bf16)v.y, (bf16)v.z, (bf16)v.w };
      *(bf16x4*)(&wp[idx * 4]) = o;
    }
    return;
  }
  const int bg = blockIdx.x;                        // 0..255
  const int b = bg >> 5, g = bg & 31;
  const int c0 = g * 16;
  const float4* p = (const float4*)(x + ((size_t)b * 512 + c0) * 1024);
  float4 v[16];
  float s = 0.f, s2 = 0.f;
#pragma unroll
  for (int i = 0; i < 16; ++i) {                     // c=i, n=4t..4t+3
    v[i] = p[t + 256 * i];
    s  += (v[i].x + v[i].y) + (v[i].z + v[i].w);
    s2 += (v[i].x * v[i].x + v[i].y * v[i].y) + (v[i].z * v[i].z + v[i].w * v[i].w);
  }
#pragma unroll
  for (int d = 1; d < 64; d <<= 1) {
    s  += __shfl_xor(s,  d);
    s2 += __shfl_xor(s2, d);
  }
  __shared__ float as[4], as2[4];
  __shared__ float scs[16], shs[16];
  if ((t & 63) == 0) { as[t >> 6] = s; as2[t >> 6] = s2; }
  __syncthreads();
  if (t < 16) {
    float S  = as[0] + as[1] + as[2] + as[3];
    float S2 = as2[0] + as2[1] + as2[2] + as2[3];
    float m  = S * (1.0f / 16384.0f);
    float rs = rsqrtf(S2 * (1.0f / 16384.0f) - m * m + 1e-5f);
    float sc = rs * gn_w[c0 + t];
    scs[t] = sc;
    shs[t] = gn_b[c0 + t] - m * sc;
  }
  __syncthreads();
  bf16* ob = xn_t + ((size_t)b * 1024 + 4 * t) * 512 + c0;
#pragma unroll
  for (int j = 0; j < 4; ++j) {                      // n = 4t + j
    bf16 tmp[16];
#pragma unroll
    for (int i = 0; i < 16; ++i) {
      float val = (j == 0) ? v[i].x : (j == 1) ? v[i].y : (j == 2) ? v[i].z : v[i].w;
      tmp[i] = (bf16)(val * scs[i] + shs[i]);
    }
    *(bf16x8*)(ob + (size_t)j * 512)     = *(bf16x8*)(tmp);
    *(bf16x8*)(ob + (size_t)j * 512 + 8) = *(bf16x8*)(tmp + 8);
  }
}

// ---------------------------------------------------------------------------
// Kernel 2: QKV GEMM, single-barrier dbuf K-loop (BK=32, 16 iters).
// Q rows (o<512) pre-scaled by 0.125*log2(e). Q,K -> qkv_t token-major.
// V blocks swap MFMA operands (D^T) so the v_t[b][h][d][n] store is
// vectorized bf16x4 along n.
__global__ __launch_bounds__(256) void qkv_gemm_kernel(
    const bf16* __restrict__ W, const bf16* __restrict__ xn_t,
    const float* __restrict__ qkv_b, bf16* __restrict__ qkv_t,
    bf16* __restrict__ v_t) {
  const int n0 = blockIdx.x * 128;
  const int o0 = blockIdx.y * 128;
  const int b  = blockIdx.z;
  __shared__ bf16 As[2][128 * 32];
  __shared__ bf16 Bs[2][128 * 32];
  const int tid = threadIdx.x, ln = tid & 63, wv = tid >> 6;
  const int mw = (wv >> 1) * 64, nw = (wv & 1) * 64;
  const int l15 = ln & 15, lg = ln >> 4;
  const bool isV = (o0 >= 1024);
  const bf16* gA = W + (size_t)o0 * 512;
  const bf16* gB = xn_t + ((size_t)b * 1024 + n0) * 512;
  f32x4 acc[4][4] = {};
  async_stage_128x32(gA, As[0], tid);
  async_stage_128x32(gB, Bs[0], tid);
  for (int it = 0; it < 16; ++it) {
    __syncthreads();                                 // publish buf[cur]
    const int cur = it & 1, nxt = cur ^ 1;
    if (it < 15) {                                   // prefetch overlaps compute
      async_stage_128x32(gA + (it + 1) * 32, As[nxt], tid);
      async_stage_128x32(gB + (it + 1) * 32, Bs[nxt], tid);
    }
    bf16x8 af[4], bfr[4];
#pragma unroll
    for (int mi = 0; mi < 4; ++mi)
      af[mi] = *(const bf16x8*)(&As[cur][(mw + mi * 16 + l15) * 32 + lg * 8]);
#pragma unroll
    for (int nj = 0; nj < 4; ++nj)
      bfr[nj] = *(const bf16x8*)(&Bs[cur][(nw + nj * 16 + l15) * 32 + lg * 8]);
    if (!isV) {
#pragma unroll
      for (int mi = 0; mi < 4; ++mi)
#pragma unroll
        for (int nj = 0; nj < 4; ++nj)
          acc[mi][nj] = MFMA_16x16x32(af[mi], bfr[nj], acc[mi][nj]);
    } else {                                         // swapped: acc = D^T
#pragma unroll
      for (int mi = 0; mi < 4; ++mi)
#pragma unroll
        for (int nj = 0; nj < 4; ++nj)
          acc[mi][nj] = MFMA_16x16x32(bfr[nj], af[mi], acc[mi][nj]);
    }
  }
  if (!isV) {
    const float qs = (o0 < 512) ? 0.125f * 1.44269504089f : 1.0f;
#pragma unroll
    for (int mi = 0; mi < 4; ++mi) {
      const int o = o0 + mw + mi * 16 + lg * 4;
      const float b0 = qkv_b[o], b1 = qkv_b[o + 1], b2 = qkv_b[o + 2], b3 = qkv_b[o + 3];
#pragma unroll
      for (int nj = 0; nj < 4; ++nj) {
        const int n = n0 + nw + nj * 16 + l15;
        f32x4 v = acc[mi][nj];
        bf16x4 st = { (bf16)((v.x + b0) * qs), (bf16)((v.y + b1) * qs),
                      (bf16)((v.z + b2) * qs), (bf16)((v.w + b3) * qs) };
        *(bf16x4*)(&qkv_t[((size_t)b * 1024 + n) * 1536 + o]) = st;
      }
    }
  } else {
    // swapped C-layout: lane holds D[n = nw+nj*16+lg*4+r][o = mw+mi*16+l15]
#pragma unroll
    for (int mi = 0; mi < 4; ++mi) {
      const int o  = o0 + mw + mi * 16 + l15;
      const int hd = o - 1024;                       // h*64 + d
      const float bias = qkv_b[o];
#pragma unroll
      for (int nj = 0; nj < 4; ++nj) {
        const int n = n0 + nw + nj * 16 + lg * 4;
        f32x4 v = acc[mi][nj];
        bf16x4 st = { (bf16)(v.x + bias), (bf16)(v.y + bias),
                      (bf16)(v.z + bias), (bf16)(v.w + bias) };
        *(bf16x4*)(&v_t[((size_t)b * 512 + hd) * 1024 + n]) = st;
      }
    }
  }
}

// ---------------------------------------------------------------------------
// Kernel 3: fused attention: S^T/O^T, dual-kv-split, no online max, K/V
// staged in LDS with register prefetch. Grid (bh, qt): XCD = bh%8 so a
// head's 8 q-tile blocks share one XCD's L2.
__global__ __launch_bounds__(512, 4) void attn_kernel(
    const bf16* __restrict__ qkv_t, const bf16* __restrict__ v_t,
    bf16* __restrict__ at_t) {
  const int qt = blockIdx.y;                        // 0..7 (128 q each)
  const int b  = blockIdx.x >> 3;
  const int h  = blockIdx.x & 7;
  __shared__ __align__(16) char smem[73728];
  const int tid = threadIdx.x, ln = tid & 63, wv = tid >> 6;
  const int half = wv >> 2, w4 = wv & 3;
  const int l15 = ln & 15, g = ln >> 4;
  bf16* Kt = (bf16*)(smem + half * 18432);          // 64 x 72
  bf16* Vt = Kt + 64 * 72;                          // 64 x 72
  bf16* Pme = (bf16*)(smem + 36864) + wv * 32 * 72; // per-wave P[q][kv]
  const bf16* hq  = qkv_t + (size_t)b * 1024 * 1536 + h * 64;
  const bf16* hk  = hq + 512;
  const bf16* vtb = v_t + (size_t)(b * 8 + h) * 64 * 1024;

  const int qb = qt * 128 + w4 * 32;
  bf16x8 qf[2][2];
#pragma unroll
  for (int m = 0; m < 2; ++m)
#pragma unroll
    for (int ks = 0; ks < 2; ++ks)
      qf[m][ks] = *(const bf16x8*)(hq + (size_t)(qb + m * 16 + l15) * 1536 + ks * 32 + g * 8);

  f32x4 oacc[2][4] = {};
  float lst[2] = { 0.f, 0.f };

  const int t256 = tid & 255;
  const int srow = t256 >> 2, scg = (t256 & 3) * 16;
  const int kt0 = half * 8;
  bf16x8 kpre0 = *(const bf16x8*)(hk + (size_t)(kt0 * 64 + srow) * 1536 + scg);
  bf16x8 kpre1 = *(const bf16x8*)(hk + (size_t)(kt0 * 64 + srow) * 1536 + scg + 8);
  bf16x8 vpre0 = *(const bf16x8*)(vtb + (size_t)srow * 1024 + kt0 * 64 + scg);
  bf16x8 vpre1 = *(const bf16x8*)(vtb + (size_t)srow * 1024 + kt0 * 64 + scg + 8);

  for (int i = 0; i < 8; ++i) {
    __syncthreads();
    *(bf16x8*)(&Kt[srow * 72 + scg])     = kpre0;
    *(bf16x8*)(&Kt[srow * 72 + scg + 8]) = kpre1;
    *(bf16x8*)(&Vt[srow * 72 + scg])     = vpre0;
    *(bf16x8*)(&Vt[srow * 72 + scg + 8]) = vpre1;
    __syncthreads();
    if (i < 7) {
      const int ktn = kt0 + i + 1;
      const bf16* hk2  = hk  + (size_t)(ktn * 64 + srow) * 1536 + scg;
      const bf16* vtb2 = vtb + (size_t)srow * 1024 + ktn * 64 + scg;
      kpre0 = *(const bf16x8*)(hk2);
      kpre1 = *(const bf16x8*)(hk2 + 8);
      vpre0 = *(const bf16x8*)(vtb2);
      vpre1 = *(const bf16x8*)(vtb2 + 8);
    }

    bf16x8 kf[4][2];
#pragma unroll
    for (int kj = 0; kj < 4; ++kj)
#pragma unroll
      for (int ks = 0; ks < 2; ++ks)
        kf[kj][ks] = *(const bf16x8*)(&Kt[(kj * 16 + l15) * 72 + ks * 32 + g * 8]);

#pragma unroll
    for (int m = 0; m < 2; ++m) {
      f32x4 st[4] = {};
#pragma unroll
      for (int ks = 0; ks < 2; ++ks)
#pragma unroll
        for (int kj = 0; kj < 4; ++kj)
          st[kj] = MFMA_16x16x32(kf[kj][ks], qf[m][ks], st[kj]);
      float rs = 0.f;
#pragma unroll
      for (int kj = 0; kj < 4; ++kj) {
        float e0 = exp2f(st[kj][0]);
        float e1 = exp2f(st[kj][1]);
        float e2 = exp2f(st[kj][2]);
        float e3 = exp2f(st[kj][3]);
        rs += (e0 + e1) + (e2 + e3);
        bf16x4 pe = { (bf16)e0, (bf16)e1, (bf16)e2, (bf16)e3 };
        *(bf16x4*)(&Pme[(m * 16 + l15) * 72 + kj * 16 + g * 4]) = pe;
      }
      lst[m] += rs;
    }

#pragma unroll
    for (int ks = 0; ks < 2; ++ks) {
      bf16x8 vf[4];
#pragma unroll
      for (int dt = 0; dt < 4; ++dt)
        vf[dt] = *(const bf16x8*)(&Vt[(dt * 16 + l15) * 72 + ks * 32 + g * 8]);
#pragma unroll
      for (int m = 0; m < 2; ++m) {
        bf16x8 pf = *(const bf16x8*)(&Pme[(m * 16 + l15) * 72 + ks * 32 + g * 8]);
#pragma unroll
        for (int dt = 0; dt < 4; ++dt)
          oacc[m][dt] = MFMA_16x16x32(vf[dt], pf, oacc[m][dt]);
      }
    }
  }

  float lfull[2];
#pragma unroll
  for (int m = 0; m < 2; ++m) {
    float l = lst[m];
    l += __shfl_xor(l, 16);
    l += __shfl_xor(l, 32);
    lfull[m] = l;
  }

  float* MB  = (float*)smem;                        // [w4][32 q][68 d-stride]
  float* MLb = (float*)(smem + 36864);              // [w4][32]
  __syncthreads();
  if (half == 1) {
    float* mb = MB + w4 * (32 * 68);
#pragma unroll
    for (int m = 0; m < 2; ++m) {
#pragma unroll
      for (int dt = 0; dt < 4; ++dt)
        *(f32x4*)(mb + (m * 16 + l15) * 68 + dt * 16 + g * 4) = oacc[m][dt];
      if (g == 0) MLb[w4 * 32 + (m * 16 + l15)] = lfull[m];
    }
  }
  __syncthreads();
  if (half == 0) {
    const float* mb = MB + w4 * (32 * 68);
#pragma unroll
    for (int m = 0; m < 2; ++m) {
      const float lB  = MLb[w4 * 32 + (m * 16 + l15)];
      const float inv = 1.0f / (lfull[m] + lB);
      const int q = qb + m * 16 + l15;
#pragma unroll
      for (int dt = 0; dt < 4; ++dt) {
        f32x4 ob = *(const f32x4*)(mb + (m * 16 + l15) * 68 + dt * 16 + g * 4);
        bf16x4 ov = { (bf16)((oacc[m][dt][0] + ob[0]) * inv),
                      (bf16)((oacc[m][dt][1] + ob[1]) * inv),
                      (bf16)((oacc[m][dt][2] + ob[2]) * inv),
                      (bf16)((oacc[m][dt][3] + ob[3]) * inv) };
        *(bf16x4*)(&at_t[((size_t)b * 1024 + q) * 512 + h * 64 + dt * 16 + g * 4]) = ov;
      }
    }
  }
}

// ---------------------------------------------------------------------------
// Kernel 4: proj GEMM + bias + residual. BM=64, single-barrier dbuf (BK=32).
__global__ __launch_bounds__(256) void proj_gemm_kernel(
    const bf16* __restrict__ at_t, const bf16* __restrict__ wp,
    const float* __restrict__ proj_b, const float* __restrict__ x,
    float* __restrict__ out) {
  const int i0 = blockIdx.x * 64;                   // token tile (64)
  const int c0 = blockIdx.y * 128;                  // out-channel tile (128)
  const int b  = blockIdx.z;
  __shared__ bf16 As[2][64 * 32];
  __shared__ bf16 Bs[2][128 * 32];
  const int tid = threadIdx.x, ln = tid & 63, wv = tid >> 6;
  const int mw = (wv >> 1) * 32, nw = (wv & 1) * 64;
  const int l15 = ln & 15, lg = ln >> 4;
  const bf16* gA = at_t + ((size_t)b * 1024 + i0) * 512;
  const bf16* gB = wp + (size_t)c0 * 512;
  f32x4 acc[2][4] = {};
  async_stage_64x32(gA, As[0], tid);
  async_stage_128x32(gB, Bs[0], tid);
  for (int it = 0; it < 16; ++it) {
    __syncthreads();
    const int cur = it & 1, nxt = cur ^ 1;
    if (it < 15) {
      async_stage_64x32(gA + (it + 1) * 32, As[nxt], tid);
      async_stage_128x32(gB + (it + 1) * 32, Bs[nxt], tid);
    }
    bf16x8 af[2], bfr[4];
#pragma unroll
    for (int mi = 0; mi < 2; ++mi)
      af[mi] = *(const bf16x8*)(&As[cur][(mw + mi * 16 + l15) * 32 + lg * 8]);
#pragma unroll
    for (int nj = 0; nj < 4; ++nj)
      bfr[nj] = *(const bf16x8*)(&Bs[cur][(nw + nj * 16 + l15) * 32 + lg * 8]);
#pragma unroll
    for (int mi = 0; mi < 2; ++mi)
#pragma unroll
      for (int nj = 0; nj < 4; ++nj)
        acc[mi][nj] = MFMA_16x16x32(af[mi], bfr[nj], acc[mi][nj]);
  }
#pragma unroll
  for (int mi = 0; mi < 2; ++mi) {
    const int i = i0 + mw + mi * 16 + lg * 4;
#pragma unroll
    for (int nj = 0; nj < 4; ++nj) {
      const int c = c0 + nw + nj * 16 + l15;
      const float bias = proj_b[c];
      const size_t off = ((size_t)b * 512 + c) * 1024 + i;
      const float4 res = *(const float4*)(x + off);
      f32x4 v = acc[mi][nj];
      float4 ov;
      ov.x = v.x + bias + res.x;
      ov.y = v.y + bias + res.y;
      ov.z = v.z + bias + res.z;
      ov.w = v.w + bias + res.w;
      *(float4*)(out + off) = ov;
    }
  }
}

// ---------------------------------------------------------------------------
extern "C" void kernel_launch(void* const* d_in, const int* in_sizes, int n_in,
                              void* d_out, int out_size, void* d_ws, size_t ws_size,
                              hipStream_t stream) {
  (void)in_sizes; (void)n_in; (void)out_size; (void)ws_size;
  const float* x      = (const float*)d_in[0];
  const float* gn_w   = (const float*)d_in[1];
  const float* gn_b   = (const float*)d_in[2];
  const float* qkv_w  = (const float*)d_in[3];
  const float* qkv_b  = (const float*)d_in[4];
  const float* proj_w = (const float*)d_in[5];
  const float* proj_b = (const float*)d_in[6];
  float* out = (float*)d_out;

  // workspace layout (~100 MB)
  char* ws = (char*)d_ws;
  bf16* wq    = (bf16*)ws;                          // [1536][512]
  bf16* wp    = wq + (size_t)1536 * 512;            // [512][512]
  bf16* xn_t  = wp + (size_t)512 * 512;             // [8][1024][512]
  bf16* qkv_t = xn_t + (size_t)8 * 1024 * 512;      // [8][1024][1536] (Q,K only)
  bf16* at_t  = qkv_t + (size_t)8 * 1024 * 1536;    // [8][1024][512]
  bf16* v_t   = at_t + (size_t)8 * 1024 * 512;      // [8][8][64][1024]

  hipLaunchKernelGGL(gn_fused_kernel, dim3(1280),     dim3(256), 0, stream,
                     x, gn_w, gn_b, qkv_w, proj_w, wq, wp, xn_t);
  hipLaunchKernelGGL(qkv_gemm_kernel, dim3(8, 12, 8), dim3(256), 0, stream,
                     wq, xn_t, qkv_b, qkv_t, v_t);
  hipLaunchKernelGGL(attn_kernel,     dim3(64, 8),    dim3(512), 0, stream,
                     qkv_t, v_t, at_t);
  hipLaunchKernelGGL(proj_gemm_kernel,dim3(16, 4, 8), dim3(256), 0, stream,
                     at_t, wp, proj_b, x, out);
}